// Round 6
// baseline (294.236 us; speedup 1.0000x reference)
//
#include <hip/hip_runtime.h>
#include <stdint.h>

#define EPSV 1e-5f

typedef int v4i __attribute__((ext_vector_type(4)));

__device__ __forceinline__ v4i mfma16(v4i a, v4i b, v4i c) {
    return __builtin_amdgcn_mfma_i32_16x16x64_i8(a, b, c, 0, 0, 0);
}

// sign-extend packed 4-bit nibbles (low/high) of a dword into 4 int8 bytes
__device__ __forceinline__ int unlo(int p) {
    int lo = p & 0x0F0F0F0F;
    return lo | ((lo & 0x08080808) * 30);   // 0x08*30=0xF0, no cross-byte carry
}
__device__ __forceinline__ int unhi(int p) {
    int hi = (p >> 4) & 0x0F0F0F0F;
    return hi | ((hi & 0x08080808) * 30);
}

// epilogue: BN + ReLU-u4-quant + requant to next layer's signed-4 code.
// (valid on pool-max of raw accs since inv>0 => monotone)
__device__ __forceinline__ int8_t q_epi(int s, float fscale, float inv, float beta,
                                        float s_relu, float s_next)
{
#pragma clang fp contract(off)
    float y = (float)s * fscale;
    y = y * inv;
    y = y + beta;
    float r = rintf(y / s_relu);
    r = fminf(fmaxf(r, 0.f), 15.f);
    float v = r * s_relu;
    float r2 = rintf(v / s_next);
    r2 = fminf(fmaxf(r2, -8.f), 7.f);
    return (int8_t)(int)r2;
}

// ---------------------------------------------------------------------------
// Per-tensor weight max-abs (atomicMax on float bits; floats >= 0). grid (16,9)
// [proven through graph-capture in rounds 2-4]
// ---------------------------------------------------------------------------
struct WPtrs { const float* w[9]; int n[9]; };

__global__ __launch_bounds__(256) void k_wmax(WPtrs a, unsigned* __restrict__ smax)
{
    const int t = blockIdx.y;
    const int n = a.n[t];
    const float* w = a.w[t];
    float m = 0.f;
    for (int i = blockIdx.x * 256 + threadIdx.x; i < n; i += 16 * 256)
        m = fmaxf(m, fabsf(w[i]));
#pragma unroll
    for (int off = 32; off > 0; off >>= 1) m = fmaxf(m, __shfl_down(m, off));
    __shared__ float red[4];
    if ((threadIdx.x & 63) == 0) red[threadIdx.x >> 6] = m;
    __syncthreads();
    if (threadIdx.x == 0) {
        m = fmaxf(fmaxf(red[0], red[1]), fmaxf(red[2], red[3]));
        atomicMax(smax + t, __float_as_uint(m));
    }
}

// ---------------------------------------------------------------------------
// Pack kernel (round-4 proven, smax-based):
//  blocks 0..206  : conv weights -> MFMA B-fragment order (52992 dwords)
//  blocks 207..209: head weights -> B-fragment order, NT=3 (768 dwords)
//  blocks 210..211: BN precompute inv/beta (8*128 floats)
// ---------------------------------------------------------------------------
struct PackArgs {
    const float* w[9];
    const float* bn[8];
    const unsigned* smax;
    int* qw;
    float* bnp;
};

#define NB_B    207
#define NB_HEAD 3
#define NB_BN   2

__global__ __launch_bounds__(256) void k_pack(PackArgs a)
{
#pragma clang fp contract(off)
    const int blk = blockIdx.x;
    if (blk < NB_B) {
        const int u = blk * 256 + threadIdx.x;   // 0..52991 (exact)
        const int bcum[9] = {0, 256, 1792, 6912, 16128, 25344, 34560, 43776, 52992};
        const int CIGA[8] = {1, 4, 8, 16, 16, 16, 16, 16};
        const int COA[8]  = {16, 32, 64, 64, 64, 64, 64, 64};
        const int NTA[8]  = {1, 2, 4, 4, 4, 4, 4, 4};
        const int CINA[8] = {3, 16, 32, 64, 64, 64, 64, 64};
        int L = 0;
        while (u >= bcum[L + 1]) ++L;
        const int rem = u - bcum[L];
        const int d = rem & 3;
        const int lane = (rem >> 2) & 63;
        const int gnt = rem >> 8;
        const int NT = NTA[L];
        const int nt = gnt % NT;
        const int g = gnt / NT;
        const int CIG = CIGA[L], CIN = CINA[L], CO = COA[L];
        const int TG = 16 / CIG;
        const int n = nt * 16 + (lane & 15);
        const float s = __uint_as_float(a.smax[L]) / 7.0f;
        const float* w = a.w[L];
        unsigned dw = 0;
        for (int jb = 0; jb < 4; ++jb) {
            const int k = 16 * (lane >> 4) + 4 * d + jb;
            const int tap = g * TG + k / (4 * CIG);
            const int ci = k % (4 * CIG);
            int qv = 0;
            if (tap < 9 && ci < CIN && n < CO) {
                float rr = rintf(w[(n * CIN + ci) * 9 + tap] / s);
                rr = fminf(fmaxf(rr, -7.f), 7.f);
                qv = (int)rr;
            }
            dw |= ((unsigned)(qv & 0xff)) << (8 * jb);
        }
        a.qw[u] = (int)dw;
    } else if (blk < NB_B + NB_HEAD) {
        const int uh = (blk - NB_B) * 256 + threadIdx.x;  // 0..767 (exact)
        const int d = uh & 3;
        const int lane = (uh >> 2) & 63;
        const int nt = uh >> 8;                            // 0..2
        const int n = nt * 16 + (lane & 15);
        const float s = __uint_as_float(a.smax[8]) / 7.0f;
        const float* w = a.w[8];
        unsigned dw = 0;
        for (int jb = 0; jb < 4; ++jb) {
            const int ci = 16 * (lane >> 4) + 4 * d + jb;   // K=64 = cin
            int qv = 0;
            if (n < 36) {
                float rr = rintf(w[n * 64 + ci] / s);
                rr = fminf(fmaxf(rr, -7.f), 7.f);
                qv = (int)rr;
            }
            dw |= ((unsigned)(qv & 0xff)) << (8 * jb);
        }
        a.qw[52992 + uh] = (int)dw;
    } else {
        const int id = (blk - NB_B - NB_HEAD) * 256 + threadIdx.x;
        if (id >= 512) return;
        const int l = id >> 6, c = id & 63;
        const int C[8] = {16, 32, 64, 64, 64, 64, 64, 64};
        if (c < C[l]) {
            const float* bn = a.bn[l];
            const int Cl = C[l];
            float g = bn[c], b = bn[Cl + c], m = bn[2 * Cl + c], v = bn[3 * Cl + c];
            float inv = g / sqrtf(v + EPSV);
            float mi = m * inv;
            a.bnp[l * 128 + c] = inv;
            a.bnp[l * 128 + 64 + c] = b - mi;
        }
    }
}

// ---------------------------------------------------------------------------
// L0 fused: double fake-quant of fp32 x (NCHW) during tile staging + MFMA conv
// 3->16ch + BN/ReLU-quant/pool/requant. out NHWC [16][160][320][16].
// grid (10, 40, 16). [round-4 proven]
// ---------------------------------------------------------------------------
__global__ __launch_bounds__(256) void k_conv0(
    const float* __restrict__ x, int8_t* __restrict__ out,
    const int* __restrict__ bfrag, const float* __restrict__ scales,
    const unsigned* __restrict__ smax, const float* __restrict__ bnp)
{
#pragma clang fp contract(off)
    __shared__ int tile[660];        // 10 * 66
    __shared__ float bnl[128];

    const int b = blockIdx.z;
    const int py0 = blockIdx.y * 4;
    const int px0 = blockIdx.x * 32;
    const int ty0 = 2 * py0 - 1;
    const int tx0 = 2 * px0 - 1;
    const float s0 = scales[0], s1 = scales[1];

    for (int i = threadIdx.x; i < 660; i += 256) {
        const int ly = i / 66;
        const int lx = i - ly * 66;
        const int gy = ty0 + ly, gx = tx0 + lx;
        int v = 0;
        if ((unsigned)gy < 320u && (unsigned)gx < 640u) {
#pragma unroll
            for (int ci = 0; ci < 3; ++ci) {
                float xv = x[((size_t)(b * 3 + ci) * 320 + gy) * 640 + gx];
                float r = rintf(xv / s0);
                r = fminf(fmaxf(r, -8.f), 7.f);
                float vv = r * s0;
                float r2 = rintf(vv / s1);
                r2 = fminf(fmaxf(r2, -8.f), 7.f);
                v |= ((int)r2 & 0xff) << (8 * ci);
            }
        }
        tile[i] = v;
    }
    if (threadIdx.x < 128) bnl[threadIdx.x] = bnp[threadIdx.x];

    const int lane = threadIdx.x & 63;
    const int wv = threadIdx.x >> 6;
    const v4i bfv = *(const v4i*)&bfrag[lane * 4];
    __syncthreads();

    const int q = lane >> 4;
    const int m = lane & 15;
    const int px_sub = m >> 2;
    const int op = m & 3;
    const int lyb = 2 * wv + (op >> 1);
    const int lxb0 = 2 * px_sub + (op & 1);

    const float fscale = scales[1] * (__uint_as_float(smax[0]) / 7.0f);
    const float s_relu = scales[10];
    const float s_next = scales[2];
    const float inv = bnl[m];
    const float beta = bnl[64 + m];
    const int py = py0 + wv;

    for (int xs = 0; xs < 8; ++xs) {
        v4i af;
#pragma unroll
        for (int d = 0; d < 4; ++d) {
            int t = 4 * q + d; t = min(t, 8);
            const int ky = (t * 11) >> 5;
            const int kx = t - 3 * ky;
            af[d] = tile[(lyb + ky) * 66 + 8 * xs + lxb0 + kx];
        }
        v4i acc = mfma16(af, bfv, (v4i){0, 0, 0, 0});
        const int px = px0 + 4 * xs + q;
        const int s = max(max(acc[0], acc[1]), max(acc[2], acc[3]));
        out[((size_t)((b * 160 + py) * 320 + px)) * 16 + m] =
            q_epi(s, fscale, inv, beta, s_relu, s_next);
    }
}

// ---------------------------------------------------------------------------
// MFMA pooled conv block (L1..L3). NHWC int8 in/out. [round-4 proven path]
// ---------------------------------------------------------------------------
template <int CIG, int CO, int H, int W, int XL>
__global__ __launch_bounds__(256) void k_mconv(
    const int8_t* __restrict__ in, int8_t* __restrict__ out,
    const int* __restrict__ bfrag, const float* __restrict__ scales,
    const unsigned* __restrict__ smax, const float* __restrict__ bnp,
    int layer, int sin_idx, int srelu_idx, int snext_idx)
{
    constexpr int NT = CO / 16;
    constexpr int TG = 16 / CIG;
    constexpr int NG = (9 + TG - 1) / TG;
    constexpr int TLH = 10;                  // 2*4+2
    constexpr int TLW = 8 * XL + 2;
    constexpr int TILE_DW = TLH * TLW * CIG;
    constexpr bool PRELOAD = (NG * NT <= 8);
    constexpr int Ho = H / 2;
    constexpr int Wo = W / 2;

    __shared__ int tile[TILE_DW];
    __shared__ float bnl[128];

    const int b = blockIdx.z;
    const int py0 = blockIdx.y * 4;
    const int px0 = blockIdx.x * (4 * XL);
    const int ty0 = 2 * py0 - 1;
    const int tx0 = 2 * px0 - 1;
    const int* gin = (const int*)in;

    for (int i = threadIdx.x; i < TILE_DW; i += 256) {
        const int cig = i & (CIG - 1);
        const int rest = i / CIG;
        const int lx = rest % TLW;
        const int ly = rest / TLW;
        const int gy = ty0 + ly, gx = tx0 + lx;
        int v = 0;
        if ((unsigned)gy < (unsigned)H && (unsigned)gx < (unsigned)W)
            v = gin[((b * H + gy) * W + gx) * CIG + cig];
        tile[i] = v;
    }
    if (threadIdx.x < 128) bnl[threadIdx.x] = bnp[layer * 128 + threadIdx.x];

    const int lane = threadIdx.x & 63;
    const int wv = threadIdx.x >> 6;
    v4i breg[PRELOAD ? NG * NT : 1];
    if constexpr (PRELOAD) {
#pragma unroll
        for (int i = 0; i < NG * NT; ++i)
            breg[i] = *(const v4i*)&bfrag[(i * 64 + lane) * 4];
    }
    __syncthreads();

    const int q = lane >> 4;
    const int m = lane & 15;

    const float fscale = scales[sin_idx] * (__uint_as_float(smax[layer]) / 7.0f);
    const float s_relu = scales[srelu_idx];
    const float s_next = scales[snext_idx];

    const int px_sub = m >> 2;
    const int op = m & 3;
    const int lyb = 2 * wv + (op >> 1);
    const int lxb0 = 2 * px_sub + (op & 1);

    for (int xs = 0; xs < XL; ++xs) {
        v4i acc[NT];
#pragma unroll
        for (int j = 0; j < NT; ++j) acc[j] = (v4i){0, 0, 0, 0};

#pragma unroll
        for (int g = 0; g < NG; ++g) {
            v4i af;
            if constexpr (CIG == 16) {
                const int ky = (g * 11) >> 5;
                const int kx = g - 3 * ky;
                const int addr = ((lyb + ky) * TLW + (8 * xs + lxb0 + kx)) * 16 + 4 * q;
                af = *(const v4i*)&tile[addr];
            } else if constexpr (CIG == 8) {
                int t = 2 * g + (q >> 1); t = min(t, 8);
                const int ky = (t * 11) >> 5;
                const int kx = t - 3 * ky;
                const int addr = ((lyb + ky) * TLW + (8 * xs + lxb0 + kx)) * 8 + 4 * (q & 1);
                af = *(const v4i*)&tile[addr];
            } else if constexpr (CIG == 4) {
                int t = 4 * g + q; t = min(t, 8);
                const int ky = (t * 11) >> 5;
                const int kx = t - 3 * ky;
                const int addr = ((lyb + ky) * TLW + (8 * xs + lxb0 + kx)) * 4;
                af = *(const v4i*)&tile[addr];
            }
#pragma unroll
            for (int j = 0; j < NT; ++j) {
                v4i bf;
                if constexpr (PRELOAD) bf = breg[g * NT + j];
                else bf = *(const v4i*)&bfrag[((g * NT + j) * 64 + lane) * 4];
                acc[j] = mfma16(af, bf, acc[j]);
            }
        }

        const int py = py0 + wv;
        const int px = px0 + 4 * xs + q;
        int8_t* po = out + ((size_t)((b * Ho + py) * Wo + px)) * CO + m;
#pragma unroll
        for (int j = 0; j < NT; ++j) {
            const int co = j * 16 + m;
            const int s = max(max(acc[j][0], acc[j][1]), max(acc[j][2], acc[j][3]));
            po[j * 16] = q_epi(s, fscale, bnl[co], bnl[64 + co], s_relu, s_next);
        }
    }
}

// ---------------------------------------------------------------------------
// Tail: L4..L7 (3x3, 64->64, 20x40) + 1x1 head (64->36) + bias, one block per
// image, activations LDS-resident as nibble-packed codes.
// Packed layout: px slot = (y+1)*42 + (x+1); 8 dwords/px; byte j of px holds
// ch j (low nibble) and ch j+32 (high nibble). Halo slots stay zero.
// grid (16), block 1024 (16 waves).
// ---------------------------------------------------------------------------
__global__ __launch_bounds__(1024) void k_tail(
    const int8_t* __restrict__ in,   // L3 out: NHWC [16][20][40][64]
    float* __restrict__ dout,        // [16][36][800]
    const int* __restrict__ qw,      // packed fragments (base)
    const float* __restrict__ scales,
    const unsigned* __restrict__ smax,
    const float* __restrict__ bnp,
    const float* __restrict__ b9)
{
    __shared__ int lbuf[2][7392];    // 2 x 22*42*8 dwords (nibble-packed)
    __shared__ float bnl[512];       // layers 4..7 inv/beta

    const int b = blockIdx.x;
    const int tid = threadIdx.x;

    for (int i = tid; i < 14784; i += 1024) ((int*)lbuf)[i] = 0;
    for (int i = tid; i < 512; i += 1024) bnl[i] = bnp[512 + i];
    __syncthreads();

    // stage L3 output -> nibble-packed lbuf[0]
    const int* g = (const int*)in + (size_t)b * 12800;
    for (int d = tid; d < 6400; d += 1024) {
        const int px = d >> 3, dd = d & 7;
        const int y = px / 40, x = px - y * 40;
        const int dwA = g[px * 16 + dd];
        const int dwB = g[px * 16 + dd + 8];
        lbuf[0][((y + 1) * 42 + (x + 1)) * 8 + dd] =
            (dwA & 0x0F0F0F0F) | ((dwB & 0x0F0F0F0F) << 4);
    }
    __syncthreads();

    const int lane = tid & 63;
    const int wv = tid >> 6;
    const int q = lane >> 4;
    const int m = lane & 15;
    const int qoff = 4 * (q & 1);
    const bool qlo = (q < 2);

    const int bo4[4] = {16128, 25344, 34560, 43776};

    for (int j = 0; j < 4; ++j) {
        const int* src = lbuf[j & 1];
        int* dst = lbuf[1 - (j & 1)];
        const int* bf = qw + bo4[j];
        const float fscale = scales[5 + j] * (__uint_as_float(smax[4 + j]) / 7.0f);
        const float s_relu = scales[14 + j];
        const float s_next = (j < 3) ? scales[6 + j] : scales[9];

        for (int item = wv; item < 100; item += 16) {
            const int t = item >> 1, ntl = item & 1;
            const int p = t * 16 + m;
            const int y = p / 40, x = p - y * 40;
            v4i acc0 = (v4i){0, 0, 0, 0}, acc1 = (v4i){0, 0, 0, 0};
#pragma unroll
            for (int g9 = 0; g9 < 9; ++g9) {
                const int ky = (g9 * 11) >> 5;
                const int kx = g9 - 3 * ky;
                const int base = ((y + ky) * 42 + (x + kx)) * 8 + qoff;
                const int4 pk = *(const int4*)&src[base];
                v4i af;
                if (qlo) { af[0] = unlo(pk.x); af[1] = unlo(pk.y); af[2] = unlo(pk.z); af[3] = unlo(pk.w); }
                else     { af[0] = unhi(pk.x); af[1] = unhi(pk.y); af[2] = unhi(pk.z); af[3] = unhi(pk.w); }
                const v4i b0 = *(const v4i*)&bf[((g9 * 4 + ntl) * 64 + lane) * 4];
                const v4i b1 = *(const v4i*)&bf[((g9 * 4 + ntl + 2) * 64 + lane) * 4];
                acc0 = mfma16(af, b0, acc0);
                acc1 = mfma16(af, b1, acc1);
            }
            const int co0 = ntl * 16 + m;
            const int co1 = co0 + 32;
            const float inv0 = bnl[j * 128 + co0], beta0 = bnl[j * 128 + 64 + co0];
            const float inv1 = bnl[j * 128 + co1], beta1 = bnl[j * 128 + 64 + co1];
#pragma unroll
            for (int r = 0; r < 4; ++r) {
                const int p2 = t * 16 + 4 * q + r;
                const int y2 = p2 / 40, x2 = p2 - y2 * 40;
                const int c0 = (int)q_epi(acc0[r], fscale, inv0, beta0, s_relu, s_next);
                const int c1 = (int)q_epi(acc1[r], fscale, inv1, beta1, s_relu, s_next);
                ((int8_t*)dst)[((y2 + 1) * 42 + (x2 + 1)) * 32 + m + 16 * ntl] =
                    (int8_t)((c0 & 0xF) | ((c1 & 0xF) << 4));
            }
        }
        __syncthreads();
    }

    // head: reads lbuf[0] (l7 output), K=64 single group
    {
#pragma clang fp contract(off)
        const int* src = lbuf[0];
        const int* hf = qw + 52992;
        const float fs = scales[9] * (__uint_as_float(smax[8]) / 7.0f);
        for (int item = wv; item < 150; item += 16) {
            const int t = item / 3, nt = item - 3 * t;
            const int p = t * 16 + m;
            const int y = p / 40, x = p - y * 40;
            const int base = ((y + 1) * 42 + (x + 1)) * 8 + qoff;
            const int4 pk = *(const int4*)&src[base];
            v4i af;
            if (qlo) { af[0] = unlo(pk.x); af[1] = unlo(pk.y); af[2] = unlo(pk.z); af[3] = unlo(pk.w); }
            else     { af[0] = unhi(pk.x); af[1] = unhi(pk.y); af[2] = unhi(pk.z); af[3] = unhi(pk.w); }
            const v4i bfv = *(const v4i*)&hf[(nt * 64 + lane) * 4];
            const v4i acc = mfma16(af, bfv, (v4i){0, 0, 0, 0});
            const int co = nt * 16 + m;
            if (co < 36) {
                const float bias = b9[co];
#pragma unroll
                for (int r = 0; r < 4; ++r) {
                    const int p2 = t * 16 + 4 * q + r;
                    float yv = (float)acc[r] * fs;
                    dout[((size_t)(b * 36 + co)) * 800 + p2] = yv + bias;
                }
            }
        }
    }
}

// ---------------------------------------------------------------------------
// Launch (9 dispatches)
// ---------------------------------------------------------------------------
extern "C" void kernel_launch(void* const* d_in, const int* in_sizes, int n_in,
                              void* d_out, int out_size, void* d_ws, size_t ws_size,
                              hipStream_t stream)
{
    const float* x = (const float*)d_in[0];
    const float* w[9];
    for (int i = 0; i < 9; i++) w[i] = (const float*)d_in[1 + i];
    const float* b9 = (const float*)d_in[10];
    const float* bn[8];
    for (int i = 0; i < 8; i++) bn[i] = (const float*)d_in[11 + i];
    const float* scales = (const float*)d_in[19];

    int8_t* base = (int8_t*)d_ws;
    int8_t* bufA = base;                             // 13,107,200 B
    int8_t* bufB = base + 13107200;                  // 13,107,200 B
    int*     qw  = (int*)(base + 26214400);          // 53760 dwords
    unsigned* smax = (unsigned*)(base + 26429440);   // 9 uints
    float*   bnp = (float*)(base + 26429952);        // 1024 floats

    static const int wn[9] = {432, 4608, 18432, 36864, 36864, 36864, 36864, 36864, 2304};
    static const int bo[8] = {0, 256, 1792, 6912, 16128, 25344, 34560, 43776};

    hipMemsetAsync(smax, 0, 9 * sizeof(unsigned), stream);

    WPtrs wp;
    for (int i = 0; i < 9; i++) { wp.w[i] = w[i]; wp.n[i] = wn[i]; }
    k_wmax<<<dim3(16, 9), 256, 0, stream>>>(wp, smax);

    PackArgs pa;
    for (int i = 0; i < 9; i++) pa.w[i] = w[i];
    for (int i = 0; i < 8; i++) pa.bn[i] = bn[i];
    pa.smax = smax; pa.qw = qw; pa.bnp = bnp;
    k_pack<<<NB_B + NB_HEAD + NB_BN, 256, 0, stream>>>(pa);

    // L0 (fused input double-quant): fp32 x -> NHWC codes, out bufB
    k_conv0<<<dim3(10, 40, 16), 256, 0, stream>>>(
        x, bufB, qw + bo[0], scales, smax, bnp);

    // L1: CIG=4, CO=32, pool, 160x320 -> 80x160
    k_mconv<4, 32, 160, 320, 4><<<dim3(10, 20, 16), 256, 0, stream>>>(
        bufB, bufA, qw + bo[1], scales, smax, bnp, 1, 2, 11, 3);
    // L2: CIG=8, CO=64, pool, 80x160 -> 40x80
    k_mconv<8, 64, 80, 160, 2><<<dim3(10, 10, 16), 256, 0, stream>>>(
        bufA, bufB, qw + bo[2], scales, smax, bnp, 2, 3, 12, 4);
    // L3: CIG=16, CO=64, pool, 40x80 -> 20x40
    k_mconv<16, 64, 40, 80, 1><<<dim3(10, 5, 16), 256, 0, stream>>>(
        bufB, bufA, qw + bo[3], scales, smax, bnp, 3, 4, 13, 5);

    // L4..L7 + head, LDS-resident
    k_tail<<<16, 1024, 0, stream>>>(
        bufA, (float*)d_out, qw, scales, smax, bnp, b9);

    (void)in_sizes; (void)n_in; (void)out_size; (void)ws_size;
}

// Round 7
// 225.331 us; speedup vs baseline: 1.3058x; 1.3058x over previous
//
#include <hip/hip_runtime.h>
#include <stdint.h>

#define EPSV 1e-5f

typedef int v4i __attribute__((ext_vector_type(4)));

__device__ __forceinline__ v4i mfma16(v4i a, v4i b, v4i c) {
    return __builtin_amdgcn_mfma_i32_16x16x64_i8(a, b, c, 0, 0, 0);
}

// sign-extend packed 4-bit nibbles (low/high) of a dword into 4 int8 bytes
__device__ __forceinline__ int unlo(int p) {
    int lo = p & 0x0F0F0F0F;
    return lo | ((lo & 0x08080808) * 30);   // 0x08*30=0xF0, no cross-byte carry
}
__device__ __forceinline__ int unhi(int p) {
    int hi = (p >> 4) & 0x0F0F0F0F;
    return hi | ((hi & 0x08080808) * 30);
}

// epilogue: BN + ReLU-u4-quant + requant to next layer's signed-4 code.
// (valid on pool-max of raw accs since inv>0 => monotone)
__device__ __forceinline__ int8_t q_epi(int s, float fscale, float inv, float beta,
                                        float s_relu, float s_next)
{
#pragma clang fp contract(off)
    float y = (float)s * fscale;
    y = y * inv;
    y = y + beta;
    float r = rintf(y / s_relu);
    r = fminf(fmaxf(r, 0.f), 15.f);
    float v = r * s_relu;
    float r2 = rintf(v / s_next);
    r2 = fminf(fmaxf(r2, -8.f), 7.f);
    return (int8_t)(int)r2;
}

// ---------------------------------------------------------------------------
// Per-tensor weight max-abs (atomicMax on float bits; floats >= 0). grid (16,9)
// [proven through graph-capture rounds 2-4, 6]
// ---------------------------------------------------------------------------
struct WPtrs { const float* w[9]; int n[9]; };

__global__ __launch_bounds__(256) void k_wmax(WPtrs a, unsigned* __restrict__ smax)
{
    const int t = blockIdx.y;
    const int n = a.n[t];
    const float* w = a.w[t];
    float m = 0.f;
    for (int i = blockIdx.x * 256 + threadIdx.x; i < n; i += 16 * 256)
        m = fmaxf(m, fabsf(w[i]));
#pragma unroll
    for (int off = 32; off > 0; off >>= 1) m = fmaxf(m, __shfl_down(m, off));
    __shared__ float red[4];
    if ((threadIdx.x & 63) == 0) red[threadIdx.x >> 6] = m;
    __syncthreads();
    if (threadIdx.x == 0) {
        m = fmaxf(fmaxf(red[0], red[1]), fmaxf(red[2], red[3]));
        atomicMax(smax + t, __float_as_uint(m));
    }
}

// ---------------------------------------------------------------------------
// Pack kernel (proven, smax-based)
// ---------------------------------------------------------------------------
struct PackArgs {
    const float* w[9];
    const float* bn[8];
    const unsigned* smax;
    int* qw;
    float* bnp;
};

#define NB_B    207
#define NB_HEAD 3
#define NB_BN   2

__global__ __launch_bounds__(256) void k_pack(PackArgs a)
{
#pragma clang fp contract(off)
    const int blk = blockIdx.x;
    if (blk < NB_B) {
        const int u = blk * 256 + threadIdx.x;   // 0..52991 (exact)
        const int bcum[9] = {0, 256, 1792, 6912, 16128, 25344, 34560, 43776, 52992};
        const int CIGA[8] = {1, 4, 8, 16, 16, 16, 16, 16};
        const int COA[8]  = {16, 32, 64, 64, 64, 64, 64, 64};
        const int NTA[8]  = {1, 2, 4, 4, 4, 4, 4, 4};
        const int CINA[8] = {3, 16, 32, 64, 64, 64, 64, 64};
        int L = 0;
        while (u >= bcum[L + 1]) ++L;
        const int rem = u - bcum[L];
        const int d = rem & 3;
        const int lane = (rem >> 2) & 63;
        const int gnt = rem >> 8;
        const int NT = NTA[L];
        const int nt = gnt % NT;
        const int g = gnt / NT;
        const int CIG = CIGA[L], CIN = CINA[L], CO = COA[L];
        const int TG = 16 / CIG;
        const int n = nt * 16 + (lane & 15);
        const float s = __uint_as_float(a.smax[L]) / 7.0f;
        const float* w = a.w[L];
        unsigned dw = 0;
        for (int jb = 0; jb < 4; ++jb) {
            const int k = 16 * (lane >> 4) + 4 * d + jb;
            const int tap = g * TG + k / (4 * CIG);
            const int ci = k % (4 * CIG);
            int qv = 0;
            if (tap < 9 && ci < CIN && n < CO) {
                float rr = rintf(w[(n * CIN + ci) * 9 + tap] / s);
                rr = fminf(fmaxf(rr, -7.f), 7.f);
                qv = (int)rr;
            }
            dw |= ((unsigned)(qv & 0xff)) << (8 * jb);
        }
        a.qw[u] = (int)dw;
    } else if (blk < NB_B + NB_HEAD) {
        const int uh = (blk - NB_B) * 256 + threadIdx.x;  // 0..767 (exact)
        const int d = uh & 3;
        const int lane = (uh >> 2) & 63;
        const int nt = uh >> 8;                            // 0..2
        const int n = nt * 16 + (lane & 15);
        const float s = __uint_as_float(a.smax[8]) / 7.0f;
        const float* w = a.w[8];
        unsigned dw = 0;
        for (int jb = 0; jb < 4; ++jb) {
            const int ci = 16 * (lane >> 4) + 4 * d + jb;   // K=64 = cin
            int qv = 0;
            if (n < 36) {
                float rr = rintf(w[n * 64 + ci] / s);
                rr = fminf(fmaxf(rr, -7.f), 7.f);
                qv = (int)rr;
            }
            dw |= ((unsigned)(qv & 0xff)) << (8 * jb);
        }
        a.qw[52992 + uh] = (int)dw;
    } else {
        const int id = (blk - NB_B - NB_HEAD) * 256 + threadIdx.x;
        if (id >= 512) return;
        const int l = id >> 6, c = id & 63;
        const int C[8] = {16, 32, 64, 64, 64, 64, 64, 64};
        if (c < C[l]) {
            const float* bn = a.bn[l];
            const int Cl = C[l];
            float g = bn[c], b = bn[Cl + c], m = bn[2 * Cl + c], v = bn[3 * Cl + c];
            float inv = g / sqrtf(v + EPSV);
            float mi = m * inv;
            a.bnp[l * 128 + c] = inv;
            a.bnp[l * 128 + 64 + c] = b - mi;
        }
    }
}

// ---------------------------------------------------------------------------
// L0 fused: double fake-quant of fp32 x (NCHW) during tile staging + MFMA conv
// 3->16ch + BN/ReLU-quant/pool/requant. out NHWC [16][160][320][16]. [proven]
// ---------------------------------------------------------------------------
__global__ __launch_bounds__(256) void k_conv0(
    const float* __restrict__ x, int8_t* __restrict__ out,
    const int* __restrict__ bfrag, const float* __restrict__ scales,
    const unsigned* __restrict__ smax, const float* __restrict__ bnp)
{
#pragma clang fp contract(off)
    __shared__ int tile[660];        // 10 * 66
    __shared__ float bnl[128];

    const int b = blockIdx.z;
    const int py0 = blockIdx.y * 4;
    const int px0 = blockIdx.x * 32;
    const int ty0 = 2 * py0 - 1;
    const int tx0 = 2 * px0 - 1;
    const float s0 = scales[0], s1 = scales[1];

    for (int i = threadIdx.x; i < 660; i += 256) {
        const int ly = i / 66;
        const int lx = i - ly * 66;
        const int gy = ty0 + ly, gx = tx0 + lx;
        int v = 0;
        if ((unsigned)gy < 320u && (unsigned)gx < 640u) {
#pragma unroll
            for (int ci = 0; ci < 3; ++ci) {
                float xv = x[((size_t)(b * 3 + ci) * 320 + gy) * 640 + gx];
                float r = rintf(xv / s0);
                r = fminf(fmaxf(r, -8.f), 7.f);
                float vv = r * s0;
                float r2 = rintf(vv / s1);
                r2 = fminf(fmaxf(r2, -8.f), 7.f);
                v |= ((int)r2 & 0xff) << (8 * ci);
            }
        }
        tile[i] = v;
    }
    if (threadIdx.x < 128) bnl[threadIdx.x] = bnp[threadIdx.x];

    const int lane = threadIdx.x & 63;
    const int wv = threadIdx.x >> 6;
    const v4i bfv = *(const v4i*)&bfrag[lane * 4];
    __syncthreads();

    const int q = lane >> 4;
    const int m = lane & 15;
    const int px_sub = m >> 2;
    const int op = m & 3;
    const int lyb = 2 * wv + (op >> 1);
    const int lxb0 = 2 * px_sub + (op & 1);

    const float fscale = scales[1] * (__uint_as_float(smax[0]) / 7.0f);
    const float s_relu = scales[10];
    const float s_next = scales[2];
    const float inv = bnl[m];
    const float beta = bnl[64 + m];
    const int py = py0 + wv;

    for (int xs = 0; xs < 8; ++xs) {
        v4i af;
#pragma unroll
        for (int d = 0; d < 4; ++d) {
            int t = 4 * q + d; t = min(t, 8);
            const int ky = (t * 11) >> 5;
            const int kx = t - 3 * ky;
            af[d] = tile[(lyb + ky) * 66 + 8 * xs + lxb0 + kx];
        }
        v4i acc = mfma16(af, bfv, (v4i){0, 0, 0, 0});
        const int px = px0 + 4 * xs + q;
        const int s = max(max(acc[0], acc[1]), max(acc[2], acc[3]));
        out[((size_t)((b * 160 + py) * 320 + px)) * 16 + m] =
            q_epi(s, fscale, inv, beta, s_relu, s_next);
    }
}

// ---------------------------------------------------------------------------
// MFMA pooled conv block (L1..L3). NHWC int8 in/out. [proven]
// ---------------------------------------------------------------------------
template <int CIG, int CO, int H, int W, int XL>
__global__ __launch_bounds__(256) void k_mconv(
    const int8_t* __restrict__ in, int8_t* __restrict__ out,
    const int* __restrict__ bfrag, const float* __restrict__ scales,
    const unsigned* __restrict__ smax, const float* __restrict__ bnp,
    int layer, int sin_idx, int srelu_idx, int snext_idx)
{
    constexpr int NT = CO / 16;
    constexpr int TG = 16 / CIG;
    constexpr int NG = (9 + TG - 1) / TG;
    constexpr int TLH = 10;                  // 2*4+2
    constexpr int TLW = 8 * XL + 2;
    constexpr int TILE_DW = TLH * TLW * CIG;
    constexpr bool PRELOAD = (NG * NT <= 8);
    constexpr int Ho = H / 2;
    constexpr int Wo = W / 2;

    __shared__ int tile[TILE_DW];
    __shared__ float bnl[128];

    const int b = blockIdx.z;
    const int py0 = blockIdx.y * 4;
    const int px0 = blockIdx.x * (4 * XL);
    const int ty0 = 2 * py0 - 1;
    const int tx0 = 2 * px0 - 1;
    const int* gin = (const int*)in;

    for (int i = threadIdx.x; i < TILE_DW; i += 256) {
        const int cig = i & (CIG - 1);
        const int rest = i / CIG;
        const int lx = rest % TLW;
        const int ly = rest / TLW;
        const int gy = ty0 + ly, gx = tx0 + lx;
        int v = 0;
        if ((unsigned)gy < (unsigned)H && (unsigned)gx < (unsigned)W)
            v = gin[((b * H + gy) * W + gx) * CIG + cig];
        tile[i] = v;
    }
    if (threadIdx.x < 128) bnl[threadIdx.x] = bnp[layer * 128 + threadIdx.x];

    const int lane = threadIdx.x & 63;
    const int wv = threadIdx.x >> 6;
    v4i breg[PRELOAD ? NG * NT : 1];
    if constexpr (PRELOAD) {
#pragma unroll
        for (int i = 0; i < NG * NT; ++i)
            breg[i] = *(const v4i*)&bfrag[(i * 64 + lane) * 4];
    }
    __syncthreads();

    const int q = lane >> 4;
    const int m = lane & 15;

    const float fscale = scales[sin_idx] * (__uint_as_float(smax[layer]) / 7.0f);
    const float s_relu = scales[srelu_idx];
    const float s_next = scales[snext_idx];

    const int px_sub = m >> 2;
    const int op = m & 3;
    const int lyb = 2 * wv + (op >> 1);
    const int lxb0 = 2 * px_sub + (op & 1);

    for (int xs = 0; xs < XL; ++xs) {
        v4i acc[NT];
#pragma unroll
        for (int j = 0; j < NT; ++j) acc[j] = (v4i){0, 0, 0, 0};

#pragma unroll
        for (int g = 0; g < NG; ++g) {
            v4i af;
            if constexpr (CIG == 16) {
                const int ky = (g * 11) >> 5;
                const int kx = g - 3 * ky;
                const int addr = ((lyb + ky) * TLW + (8 * xs + lxb0 + kx)) * 16 + 4 * q;
                af = *(const v4i*)&tile[addr];
            } else if constexpr (CIG == 8) {
                int t = 2 * g + (q >> 1); t = min(t, 8);
                const int ky = (t * 11) >> 5;
                const int kx = t - 3 * ky;
                const int addr = ((lyb + ky) * TLW + (8 * xs + lxb0 + kx)) * 8 + 4 * (q & 1);
                af = *(const v4i*)&tile[addr];
            } else if constexpr (CIG == 4) {
                int t = 4 * g + q; t = min(t, 8);
                const int ky = (t * 11) >> 5;
                const int kx = t - 3 * ky;
                const int addr = ((lyb + ky) * TLW + (8 * xs + lxb0 + kx)) * 4;
                af = *(const v4i*)&tile[addr];
            }
#pragma unroll
            for (int j = 0; j < NT; ++j) {
                v4i bf;
                if constexpr (PRELOAD) bf = breg[g * NT + j];
                else bf = *(const v4i*)&bfrag[((g * NT + j) * 64 + lane) * 4];
                acc[j] = mfma16(af, bf, acc[j]);
            }
        }

        const int py = py0 + wv;
        const int px = px0 + 4 * xs + q;
        int8_t* po = out + ((size_t)((b * Ho + py) * Wo + px)) * CO + m;
#pragma unroll
        for (int j = 0; j < NT; ++j) {
            const int co = j * 16 + m;
            const int s = max(max(acc[j][0], acc[j][1]), max(acc[j][2], acc[j][3]));
            po[j * 16] = q_epi(s, fscale, bnl[co], bnl[64 + co], s_relu, s_next);
        }
    }
}

// ---------------------------------------------------------------------------
// Tail: L4..L7 + head, redundant-halo strips. grid (8, 16) = strip x image,
// 512 threads. Each block owns a width-5 x-strip, stages strip+halo of the
// L3 output nibble-packed in LDS, computes shrinking regions per layer
// (width 11/9/7/5), then the head on its own 5 columns. Strips overlap-
// compute halo px (bit-identical integer math); no inter-block deps.
// Slot layout: row slot = gy+1 (22 rows), col slot = gx-x0+5 (15 cols),
// 8 dwords/px, byte j = ch j (lo nibble) | ch j+32 (hi nibble).
// ---------------------------------------------------------------------------
__global__ __launch_bounds__(512) void k_tail(
    const int8_t* __restrict__ in,   // L3 out: NHWC [16][20][40][64]
    float* __restrict__ dout,        // [16][36][800]
    const int* __restrict__ qw,
    const float* __restrict__ scales,
    const unsigned* __restrict__ smax,
    const float* __restrict__ bnp,
    const float* __restrict__ b9)
{
    __shared__ int lbuf[2][2640];    // 2 x 22*15*8 dwords
    __shared__ float bnl[512];

    const int x0 = blockIdx.x * 5;
    const int b = blockIdx.y;
    const int tid = threadIdx.x;

    // stage (zero + nibble-pack strip cols x0-4..x0+8) and zero buf1
    const int* g = (const int*)in + (size_t)b * 12800;
    for (int i = tid; i < 2640; i += 512) {
        const int dd = i & 7;
        const int s = i >> 3;
        const int cs = s % 15;
        const int rs = s / 15;
        const int gy = rs - 1;
        const int gx = x0 - 5 + cs;
        int v = 0;
        if ((unsigned)gy < 20u && cs >= 1 && cs <= 13 && (unsigned)gx < 40u) {
            const int dwA = g[(gy * 40 + gx) * 16 + dd];
            const int dwB = g[(gy * 40 + gx) * 16 + dd + 8];
            v = (dwA & 0x0F0F0F0F) | ((dwB & 0x0F0F0F0F) << 4);
        }
        lbuf[0][i] = v;
        lbuf[1][i] = 0;
    }
    bnl[tid] = bnp[512 + tid];

    const int lane = tid & 63;
    const int wv = tid >> 6;
    const int q = lane >> 4;
    const int m = lane & 15;
    const int qoff = 4 * (q & 1);
    const bool qlo = (q < 2);

    const int bo4[4] = {16128, 25344, 34560, 43776};

    for (int j = 0; j < 4; ++j) {
        __syncthreads();
        const int* src = lbuf[j & 1];
        int* dst = lbuf[1 - (j & 1)];
        const int* bf = qw + bo4[j];
        const float fscale = scales[5 + j] * (__uint_as_float(smax[4 + j]) / 7.0f);
        const float s_relu = scales[14 + j];
        const float s_next = (j < 3) ? scales[6 + j] : scales[9];
        const int xlo = max(0, x0 - 3 + j);
        const int xhi = min(39, x0 + 7 - j);
        const int w = xhi - xlo + 1;
        const int npx = 20 * w;
        const int ntile = (npx + 15) >> 4;

        for (int item = wv; item < 2 * ntile; item += 8) {
            const int t = item >> 1, ntl = item & 1;
            int p = t * 16 + m;
            if (p >= npx) p = 0;
            const int y = p / w;
            const int x = xlo + (p - y * w);
            const int sx = x - x0 + 4;          // + kx -> col slot
            v4i acc0 = (v4i){0, 0, 0, 0}, acc1 = (v4i){0, 0, 0, 0};
#pragma unroll
            for (int g9 = 0; g9 < 9; ++g9) {
                const int ky = (g9 * 11) >> 5;
                const int kx = g9 - 3 * ky;
                const int base = ((y + ky) * 15 + sx + kx) * 8 + qoff;
                const int4 pk = *(const int4*)&src[base];
                v4i af;
                if (qlo) { af[0] = unlo(pk.x); af[1] = unlo(pk.y); af[2] = unlo(pk.z); af[3] = unlo(pk.w); }
                else     { af[0] = unhi(pk.x); af[1] = unhi(pk.y); af[2] = unhi(pk.z); af[3] = unhi(pk.w); }
                const v4i b0 = *(const v4i*)&bf[((g9 * 4 + ntl) * 64 + lane) * 4];
                const v4i b1 = *(const v4i*)&bf[((g9 * 4 + ntl + 2) * 64 + lane) * 4];
                acc0 = mfma16(af, b0, acc0);
                acc1 = mfma16(af, b1, acc1);
            }
            const int co0 = ntl * 16 + m;
            const int co1 = co0 + 32;
            const float inv0 = bnl[j * 128 + co0], beta0 = bnl[j * 128 + 64 + co0];
            const float inv1 = bnl[j * 128 + co1], beta1 = bnl[j * 128 + 64 + co1];
#pragma unroll
            for (int r = 0; r < 4; ++r) {
                const int p2 = t * 16 + 4 * q + r;
                if (p2 < npx) {
                    const int y2 = p2 / w;
                    const int x2 = xlo + (p2 - y2 * w);
                    const int c0 = (int)q_epi(acc0[r], fscale, inv0, beta0, s_relu, s_next);
                    const int c1 = (int)q_epi(acc1[r], fscale, inv1, beta1, s_relu, s_next);
                    ((int8_t*)dst)[((y2 + 1) * 15 + (x2 - x0 + 5)) * 32 + m + 16 * ntl] =
                        (int8_t)((c0 & 0xF) | ((c1 & 0xF) << 4));
                }
            }
        }
    }

    __syncthreads();

    // head: reads lbuf[0] (L7 output), 5 cols x 20 rows = 100 px, K=64
    {
#pragma clang fp contract(off)
        const int* src = lbuf[0];
        const int* hf = qw + 52992;
        const float fs = scales[9] * (__uint_as_float(smax[8]) / 7.0f);
        for (int item = wv; item < 21; item += 8) {   // 7 tiles x 3 nt
            const int t = item / 3, nt = item - 3 * t;
            int p = t * 16 + m;
            if (p >= 100) p = 0;
            const int y = p / 5;
            const int x = x0 + (p - y * 5);
            const int base = ((y + 1) * 15 + (x - x0 + 5)) * 8 + qoff;
            const int4 pk = *(const int4*)&src[base];
            v4i af;
            if (qlo) { af[0] = unlo(pk.x); af[1] = unlo(pk.y); af[2] = unlo(pk.z); af[3] = unlo(pk.w); }
            else     { af[0] = unhi(pk.x); af[1] = unhi(pk.y); af[2] = unhi(pk.z); af[3] = unhi(pk.w); }
            const v4i bfv = *(const v4i*)&hf[(nt * 64 + lane) * 4];
            const v4i acc = mfma16(af, bfv, (v4i){0, 0, 0, 0});
            const int co = nt * 16 + m;
            if (co < 36) {
                const float bias = b9[co];
#pragma unroll
                for (int r = 0; r < 4; ++r) {
                    const int p2 = t * 16 + 4 * q + r;
                    if (p2 < 100) {
                        const int y2 = p2 / 5;
                        const int x2 = x0 + (p2 - y2 * 5);
                        float yv = (float)acc[r] * fs;
                        dout[((size_t)(b * 36 + co)) * 800 + y2 * 40 + x2] = yv + bias;
                    }
                }
            }
        }
    }
}

// ---------------------------------------------------------------------------
// Launch (9 dispatches)
// ---------------------------------------------------------------------------
extern "C" void kernel_launch(void* const* d_in, const int* in_sizes, int n_in,
                              void* d_out, int out_size, void* d_ws, size_t ws_size,
                              hipStream_t stream)
{
    const float* x = (const float*)d_in[0];
    const float* w[9];
    for (int i = 0; i < 9; i++) w[i] = (const float*)d_in[1 + i];
    const float* b9 = (const float*)d_in[10];
    const float* bn[8];
    for (int i = 0; i < 8; i++) bn[i] = (const float*)d_in[11 + i];
    const float* scales = (const float*)d_in[19];

    int8_t* base = (int8_t*)d_ws;
    int8_t* bufA = base;                             // 13,107,200 B
    int8_t* bufB = base + 13107200;                  // 13,107,200 B
    int*     qw  = (int*)(base + 26214400);          // 53760 dwords
    unsigned* smax = (unsigned*)(base + 26429440);   // 9 uints
    float*   bnp = (float*)(base + 26429952);        // 1024 floats

    static const int wn[9] = {432, 4608, 18432, 36864, 36864, 36864, 36864, 36864, 2304};
    static const int bo[8] = {0, 256, 1792, 6912, 16128, 25344, 34560, 43776};

    hipMemsetAsync(smax, 0, 9 * sizeof(unsigned), stream);

    WPtrs wp;
    for (int i = 0; i < 9; i++) { wp.w[i] = w[i]; wp.n[i] = wn[i]; }
    k_wmax<<<dim3(16, 9), 256, 0, stream>>>(wp, smax);

    PackArgs pa;
    for (int i = 0; i < 9; i++) pa.w[i] = w[i];
    for (int i = 0; i < 8; i++) pa.bn[i] = bn[i];
    pa.smax = smax; pa.qw = qw; pa.bnp = bnp;
    k_pack<<<NB_B + NB_HEAD + NB_BN, 256, 0, stream>>>(pa);

    // L0 (fused input double-quant): fp32 x -> NHWC codes, out bufB
    k_conv0<<<dim3(10, 40, 16), 256, 0, stream>>>(
        x, bufB, qw + bo[0], scales, smax, bnp);

    // L1: CIG=4, CO=32, pool, 160x320 -> 80x160
    k_mconv<4, 32, 160, 320, 4><<<dim3(10, 20, 16), 256, 0, stream>>>(
        bufB, bufA, qw + bo[1], scales, smax, bnp, 1, 2, 11, 3);
    // L2: CIG=8, CO=64, pool, 80x160 -> 40x80
    k_mconv<8, 64, 80, 160, 2><<<dim3(10, 10, 16), 256, 0, stream>>>(
        bufA, bufB, qw + bo[2], scales, smax, bnp, 2, 3, 12, 4);
    // L3: CIG=16, CO=64, pool, 40x80 -> 20x40
    k_mconv<16, 64, 40, 80, 1><<<dim3(10, 5, 16), 256, 0, stream>>>(
        bufB, bufA, qw + bo[3], scales, smax, bnp, 3, 4, 13, 5);

    // L4..L7 + head, LDS-resident, redundant-halo strips
    k_tail<<<dim3(8, 16), 512, 0, stream>>>(
        bufA, (float*)d_out, qw, scales, smax, bnp, b9);

    (void)in_sizes; (void)n_in; (void)out_size; (void)ws_size;
}